// Round 5
// baseline (322.422 us; speedup 1.0000x reference)
//
#include <hip/hip_runtime.h>
#include <hip/hip_bf16.h>

typedef __hip_bfloat16 bf16;
typedef __attribute__((ext_vector_type(8))) __bf16 bf16x8;
typedef __attribute__((ext_vector_type(4))) __bf16 bf16x4;
typedef __attribute__((ext_vector_type(4))) float f32x4;

constexpr int S_LEN = 2048;
constexpr int HID   = 2560;
constexpr int NH    = 40;
constexpr int QL    = 768;
constexpr int KVL   = 256;
constexpr int RD    = 32;
constexpr int ND    = 64;
constexpr int VD    = 64;
constexpr int QHD   = 96;                 // NOPE_D + ROPE_D
constexpr int QB_N  = NH * QHD;           // 3840
constexpr int KVB_N = NH * (ND + VD);     // 5120
constexpr int CKV_N = KVL + RD;           // 288
constexpr int AB_N  = QL + CKV_N;         // 1056 (fused qa|kva output cols)

#define MFMA16(a, b, c) __builtin_amdgcn_mfma_f32_16x16x32_bf16((a), (b), (c), 0, 0, 0)

// position_ids may arrive as int32 or int64; values are 0..2047 so sniff layout.
__device__ __forceinline__ int get_pos(const int* pos, int s) {
  bool is64 = (pos[1] == 0 && pos[2] == 1);
  return is64 ? pos[2 * s] : pos[s];
}

// ---------------- prep ----------------

__global__ void cast_f32_bf16(const float* __restrict__ src, bf16* __restrict__ dst, int n4) {
  int i = blockIdx.x * blockDim.x + threadIdx.x;
  if (i >= n4) return;
  float4 v = reinterpret_cast<const float4*>(src)[i];
  struct { bf16 a, b, c, d; } pk;
  pk.a = __float2bfloat16(v.x); pk.b = __float2bfloat16(v.y);
  pk.c = __float2bfloat16(v.z); pk.d = __float2bfloat16(v.w);
  reinterpret_cast<uint2*>(dst)[i] = *reinterpret_cast<uint2*>(&pk);
}

// src [K][N] f32 -> dst [N][K] bf16  (B^T layout for the GEMMs)
__global__ void transpose_cast(const float* __restrict__ src, bf16* __restrict__ dst, int K, int N) {
  __shared__ float tile[32][33];
  int nb = blockIdx.x * 32, kb = blockIdx.y * 32;
  int x = threadIdx.x, y = threadIdx.y; // (32,8)
#pragma unroll
  for (int j = 0; j < 4; ++j) {
    int k = kb + y + j * 8, n = nb + x;
    tile[y + j * 8][x] = (k < K && n < N) ? src[(size_t)k * N + n] : 0.f;
  }
  __syncthreads();
#pragma unroll
  for (int j = 0; j < 4; ++j) {
    int n = nb + y + j * 8, k = kb + x;
    if (n < N && k < K) dst[(size_t)n * K + k] = __float2bfloat16(tile[x][y + j * 8]);
  }
}

// ---------------- GEMM: C[M][N] = A[M][K] * B^T[N][K], bf16 in, f32 acc ----------------

template<bool OBF16, bool NEDGE>
__global__ __launch_bounds__(256) void gemm_bt(const bf16* __restrict__ A,
                                               const bf16* __restrict__ B,
                                               void* __restrict__ Cv,
                                               int M, int N, int K) {
  constexpr int BM = 128, BN = 128, BK = 64;
  __shared__ __bf16 ldsA[BM * BK];
  __shared__ __bf16 ldsB[BN * BK];
  const int t = threadIdx.x;
  const int l = t & 63, w = t >> 6;
  const int lr = l & 15, lk = l >> 4;
  const int wr = w >> 1, wc = w & 1;
  const int rowbase = blockIdx.y * BM;
  const int colbase = blockIdx.x * BN;

  f32x4 acc[4][4];
#pragma unroll
  for (int m = 0; m < 4; ++m)
#pragma unroll
    for (int n = 0; n < 4; ++n) acc[m][n] = f32x4{0.f, 0.f, 0.f, 0.f};

  const int kiters = K / BK;
  for (int kt = 0; kt < kiters; ++kt) {
    const int kb = kt * BK;
    // stage A,B tiles: linear LDS dest, inverse-swizzled global source (rule #21)
#pragma unroll
    for (int it = 0; it < 4; ++it) {
      const int r  = it * 32 + w * 8 + (l >> 3);
      const int c8 = ((l & 7) * 8) ^ ((r & 7) << 3); // element-units, 16B chunks
      const bf16* ga = A + (size_t)(rowbase + r) * K + kb + c8;
      __builtin_amdgcn_global_load_lds((const __attribute__((address_space(1))) void*)ga,
          (__attribute__((address_space(3))) void*)(ldsA + it * 2048 + w * 512), 16, 0, 0);
      int nrow = colbase + r;
      if (NEDGE) nrow = (nrow < N) ? nrow : (N - 1);
      const bf16* gb = B + (size_t)nrow * K + kb + c8;
      __builtin_amdgcn_global_load_lds((const __attribute__((address_space(1))) void*)gb,
          (__attribute__((address_space(3))) void*)(ldsB + it * 2048 + w * 512), 16, 0, 0);
    }
    __syncthreads();
#pragma unroll
    for (int kk = 0; kk < 2; ++kk) {
      bf16x8 af[4], bfr[4];
#pragma unroll
      for (int m = 0; m < 4; ++m) {
        const int row = wr * 64 + m * 16 + lr;
        const int ce  = (kk * 32 + lk * 8) ^ ((row & 7) << 3);
        af[m] = *(const bf16x8*)(ldsA + row * BK + ce);
      }
#pragma unroll
      for (int n = 0; n < 4; ++n) {
        const int row = wc * 64 + n * 16 + lr;
        const int ce  = (kk * 32 + lk * 8) ^ ((row & 7) << 3);
        bfr[n] = *(const bf16x8*)(ldsB + row * BK + ce);
      }
#pragma unroll
      for (int m = 0; m < 4; ++m)
#pragma unroll
        for (int n = 0; n < 4; ++n)
          acc[m][n] = MFMA16(af[m], bfr[n], acc[m][n]);
    }
    __syncthreads();
  }

  // epilogue: C row=(lk*4+i), col=lr within each 16x16 frag
#pragma unroll
  for (int m = 0; m < 4; ++m)
#pragma unroll
    for (int n = 0; n < 4; ++n) {
      const int col = colbase + wc * 64 + n * 16 + lr;
      if (NEDGE && col >= N) continue;
#pragma unroll
      for (int i = 0; i < 4; ++i) {
        const int row = rowbase + wr * 64 + m * 16 + lk * 4 + i;
        if (OBF16) ((bf16*)Cv)[(size_t)row * N + col] = __float2bfloat16(acc[m][n][i]);
        else       ((float*)Cv)[(size_t)row * N + col] = acc[m][n][i];
      }
    }
}

// Fused qa|kva GEMM: C[2048][1056] = hid_bf * wabT^T, BN=64 tiles (4 waves
// stacked in M, 32 rows x 64 cols each) for occupancy on the skinny N.
// cols 0..767 -> q_out (stride 768), cols 768..1055 -> ckv_out (stride 288).
__global__ __launch_bounds__(256) void gemm_qakva(const bf16* __restrict__ A,
                                                  const bf16* __restrict__ B,
                                                  float* __restrict__ q_out,
                                                  float* __restrict__ ckv_out) {
  constexpr int BM = 128, BK = 64, K = HID, N = AB_N;
  __shared__ __bf16 ldsA[BM * BK]; // 16KB
  __shared__ __bf16 ldsB[64 * BK]; // 8KB
  const int t = threadIdx.x;
  const int l = t & 63, w = t >> 6;
  const int lr = l & 15, lk = l >> 4;
  const int rowbase = blockIdx.y * BM;
  const int colbase = blockIdx.x * 64;

  f32x4 acc[2][4];
#pragma unroll
  for (int m = 0; m < 2; ++m)
#pragma unroll
    for (int n = 0; n < 4; ++n) acc[m][n] = f32x4{0.f, 0.f, 0.f, 0.f};

  for (int kt = 0; kt < K / BK; ++kt) {
    const int kb = kt * BK;
#pragma unroll
    for (int it = 0; it < 4; ++it) {
      const int r  = it * 32 + w * 8 + (l >> 3);
      const int c8 = ((l & 7) * 8) ^ ((r & 7) << 3);
      const bf16* ga = A + (size_t)(rowbase + r) * K + kb + c8;
      __builtin_amdgcn_global_load_lds((const __attribute__((address_space(1))) void*)ga,
          (__attribute__((address_space(3))) void*)(ldsA + it * 2048 + w * 512), 16, 0, 0);
      if (it < 2) {
        int nrow = colbase + r;
        nrow = (nrow < N) ? nrow : (N - 1);
        const bf16* gb = B + (size_t)nrow * K + kb + c8;
        __builtin_amdgcn_global_load_lds((const __attribute__((address_space(1))) void*)gb,
            (__attribute__((address_space(3))) void*)(ldsB + it * 2048 + w * 512), 16, 0, 0);
      }
    }
    __syncthreads();
#pragma unroll
    for (int kk = 0; kk < 2; ++kk) {
      bf16x8 af[2], bfr[4];
#pragma unroll
      for (int m = 0; m < 2; ++m) {
        const int row = w * 32 + m * 16 + lr;
        const int ce  = (kk * 32 + lk * 8) ^ ((row & 7) << 3);
        af[m] = *(const bf16x8*)(ldsA + row * BK + ce);
      }
#pragma unroll
      for (int n = 0; n < 4; ++n) {
        const int row = n * 16 + lr;
        const int ce  = (kk * 32 + lk * 8) ^ ((row & 7) << 3);
        bfr[n] = *(const bf16x8*)(ldsB + row * BK + ce);
      }
#pragma unroll
      for (int m = 0; m < 2; ++m)
#pragma unroll
        for (int n = 0; n < 4; ++n)
          acc[m][n] = MFMA16(af[m], bfr[n], acc[m][n]);
    }
    __syncthreads();
  }

#pragma unroll
  for (int m = 0; m < 2; ++m)
#pragma unroll
    for (int n = 0; n < 4; ++n) {
      const int col = colbase + n * 16 + lr;
#pragma unroll
      for (int i = 0; i < 4; ++i) {
        const int row = rowbase + w * 32 + m * 16 + lk * 4 + i;
        if (col < QL)       q_out[(size_t)row * QL + col] = acc[m][n][i];
        else if (col < N)   ckv_out[(size_t)row * CKV_N + (col - QL)] = acc[m][n][i];
      }
    }
}

// ---------------- norms / rope / reshapes ----------------

__global__ void rmsnorm_rows(const float* __restrict__ in, const float* __restrict__ w,
                             bf16* __restrict__ out, int C) {
  const int r = blockIdx.x;
  const float* row = in + (size_t)r * C;
  float ss = 0.f;
  for (int c = threadIdx.x; c < C; c += 256) { float v = row[c]; ss += v * v; }
#pragma unroll
  for (int d = 32; d > 0; d >>= 1) ss += __shfl_xor(ss, d);
  __shared__ float red[4];
  if ((threadIdx.x & 63) == 0) red[threadIdx.x >> 6] = ss;
  __syncthreads();
  const float tot = red[0] + red[1] + red[2] + red[3];
  const float rs = rsqrtf(tot / (float)C + 1e-6f);
  for (int c = threadIdx.x; c < C; c += 256)
    out[(size_t)r * C + c] = __float2bfloat16(row[c] * rs * w[c]);
}

// per row: rmsnorm(ckv[0:256]) -> bf16 ; rope(k_pe = ckv[256:288]) -> bf16
__global__ void kv_prep(const float* __restrict__ ckv, const float* __restrict__ w,
                        const int* __restrict__ pos, bf16* __restrict__ ckv_bf,
                        bf16* __restrict__ kpe) {
  const int s = blockIdx.x, t = threadIdx.x; // 64 threads
  const float* row = ckv + (size_t)s * CKV_N;
  float v[4]; float ss = 0.f;
#pragma unroll
  for (int j = 0; j < 4; ++j) { v[j] = row[t + 64 * j]; ss += v[j] * v[j]; }
#pragma unroll
  for (int d = 32; d > 0; d >>= 1) ss += __shfl_xor(ss, d);
  const float rs = rsqrtf(ss / (float)KVL + 1e-6f);
#pragma unroll
  for (int j = 0; j < 4; ++j)
    ckv_bf[(size_t)s * KVL + t + 64 * j] = __float2bfloat16(v[j] * rs * w[t + 64 * j]);
  if (t < 16) {
    const float x0 = row[KVL + t], x1 = row[KVL + 16 + t];
    const float p = (float)get_pos(pos, s);
    const float invf = exp2f(-(float)t * (13.2877124f / 16.f)); // 10000^(-t/16)
    const float ang = p * invf, c = cosf(ang), sn = sinf(ang);
    kpe[(size_t)s * RD + t]      = __float2bfloat16(x0 * c - x1 * sn);
    kpe[(size_t)s * RD + 16 + t] = __float2bfloat16(x1 * c + x0 * sn);
  }
}

// qraw [S][3840] -> qfull [NH][S][96], rope on last 32, * (96^-0.5 * log2e)
// grid (S), block (96,4): trig computed once per thread, looped over heads.
__global__ void rope_q(const bf16* __restrict__ qraw, const int* __restrict__ pos,
                       bf16* __restrict__ qfull) {
  const int s = blockIdx.x, d = threadIdx.x; // 0..95
  const float scale = 0.14724444f;           // 96^-0.5 * log2(e)
  float c = 0.f, sn = 0.f;
  if (d >= ND) {
    const int j = (d - ND) & 15;
    const float p = (float)get_pos(pos, s);
    const float invf = exp2f(-(float)j * (13.2877124f / 16.f));
    const float ang = p * invf;
    c = cosf(ang); sn = sinf(ang);
  }
  for (int h = threadIdx.y; h < NH; h += 4) {
    const size_t src = (size_t)s * QB_N + h * QHD;
    float outv;
    if (d < ND) {
      outv = __bfloat162float(qraw[src + d]);
    } else {
      const int j = (d - ND) & 15;
      const float x0 = __bfloat162float(qraw[src + ND + j]);
      const float x1 = __bfloat162float(qraw[src + ND + 16 + j]);
      outv = (d < ND + 16) ? (x0 * c - x1 * sn) : (x1 * c + x0 * sn);
    }
    qfull[((size_t)h * S_LEN + s) * QHD + d] = __float2bfloat16(outv * scale);
  }
}

// grid (S), block (96,4)
__global__ void build_kfull(const bf16* __restrict__ kv, const bf16* __restrict__ kpe,
                            bf16* __restrict__ kfull) {
  const int s = blockIdx.x, d = threadIdx.x; // 0..95
  bf16 pe;
  if (d >= ND) pe = kpe[(size_t)s * RD + (d - ND)];
  for (int h = threadIdx.y; h < NH; h += 4) {
    bf16 v = (d < ND) ? kv[(size_t)s * KVB_N + h * (ND + VD) + d] : pe;
    kfull[((size_t)h * S_LEN + s) * QHD + d] = v;
  }
}

// V part of kv [S][5120] -> vt [NH][64][S]
__global__ void transpose_v(const bf16* __restrict__ kv, bf16* __restrict__ vt) {
  __shared__ bf16 tile[32][33];
  const int h = blockIdx.z;
  const int sb = blockIdx.x * 32, db = blockIdx.y * 32;
  const int x = threadIdx.x, y = threadIdx.y; // (32,8)
#pragma unroll
  for (int j = 0; j < 4; ++j)
    tile[y + j * 8][x] = kv[(size_t)(sb + y + j * 8) * KVB_N + h * (ND + VD) + ND + db + x];
  __syncthreads();
#pragma unroll
  for (int j = 0; j < 4; ++j)
    vt[((size_t)h * VD + db + y + j * 8) * S_LEN + sb + x] = tile[x][y + j * 8];
}

// ---------------- causal flash attention ----------------
// Block = (head, 32 q rows), 4 waves SPLIT-K: wave w handles k-tiles w, w+4,
// w+8, ... (KVBLK=64 each, K prefetch at stride 256). Each wave keeps private
// (m, l, O) using swapped QK^T (st = mfma(K,Q) -> S^T: lane-local row reduce +
// 2 shfl), log2-domain softmax, defer-rescale, XOR-swizzled per-wave P tile.
// Epilogue: partials -> LDS, 2^(m_w - M) weighted combine by all 256 threads.
// Grid (NH, S/32), q-tiles REVERSED (heavy first -> LPT).
__global__ __launch_bounds__(256) void attn_kernel(const bf16* __restrict__ qfull,
                                                   const bf16* __restrict__ kfull,
                                                   const bf16* __restrict__ vt,
                                                   bf16* __restrict__ ctx) {
  const int h = blockIdx.x;
  const int qw = ((int)gridDim.y - 1 - (int)blockIdx.y) * 32;
  const int t = threadIdx.x;
  const int w = t >> 6, l = t & 63;
  const int lr = l & 15, lk = l >> 4;
  const bf16* Q  = qfull + (size_t)h * S_LEN * QHD;
  const bf16* Kf = kfull + (size_t)h * S_LEN * QHD;
  const bf16* V  = vt + (size_t)h * VD * S_LEN;
  __shared__ __bf16 plds[4][32][64];   // per-wave P tile, XOR-swizzled
  __shared__ __bf16 cmbO[4][32][72];   // per-wave O partials (72: 16B-aligned rows, bank-skewed)
  __shared__ float m_lds[4][32], l_lds[4][32];

  bf16x8 qf[2][3];
#pragma unroll
  for (int qg = 0; qg < 2; ++qg)
#pragma unroll
    for (int ks = 0; ks < 3; ++ks)
      qf[qg][ks] = *(const bf16x8*)(Q + (size_t)(qw + qg * 16 + lr) * QHD + ks * 32 + lk * 8);

  f32x4 o[2][4];
  float mrow[2], lrow[2];
#pragma unroll
  for (int qg = 0; qg < 2; ++qg) {
#pragma unroll
    for (int dt = 0; dt < 4; ++dt) o[qg][dt] = f32x4{0.f, 0.f, 0.f, 0.f};
    mrow[qg] = -1e30f; lrow[qg] = 0.f;
  }

  // preload this wave's first K tile
  const int kb0 = w * 64;
  bf16x8 kf[4][3];
  if (kb0 <= qw) {
#pragma unroll
    for (int sub = 0; sub < 4; ++sub)
#pragma unroll
      for (int ks = 0; ks < 3; ++ks)
        kf[sub][ks] = *(const bf16x8*)(Kf + (size_t)(kb0 + sub * 16 + lr) * QHD + ks * 32 + lk * 8);
  }

  for (int kb = kb0; kb <= qw; kb += 256) {
    // S^T tile: st[qg][sub][i] = S[q = qw+qg*16+lr][k = kb+sub*16+lk*4+i]
    f32x4 st[2][4];
#pragma unroll
    for (int qg = 0; qg < 2; ++qg)
#pragma unroll
      for (int sub = 0; sub < 4; ++sub) st[qg][sub] = f32x4{0.f, 0.f, 0.f, 0.f};
#pragma unroll
    for (int qg = 0; qg < 2; ++qg)
#pragma unroll
      for (int sub = 0; sub < 4; ++sub)
#pragma unroll
        for (int ks = 0; ks < 3; ++ks)
          st[qg][sub] = MFMA16(kf[sub][ks], qf[qg][ks], st[qg][sub]);

    // prefetch this wave's next K tile (hidden under softmax+PV)
    const int nkb = kb + 256;
    if (nkb <= qw) {
#pragma unroll
      for (int sub = 0; sub < 4; ++sub)
#pragma unroll
        for (int ks = 0; ks < 3; ++ks)
          kf[sub][ks] = *(const bf16x8*)(Kf + (size_t)(nkb + sub * 16 + lr) * QHD + ks * 32 + lk * 8);
    }

    const bool diag = (kb + 64 > qw);
    float tm[2];
#pragma unroll
    for (int qg = 0; qg < 2; ++qg) {
      const int q = qw + qg * 16 + lr;
      if (diag) {
#pragma unroll
        for (int sub = 0; sub < 4; ++sub)
#pragma unroll
          for (int i = 0; i < 4; ++i)
            if (kb + sub * 16 + lk * 4 + i > q) st[qg][sub][i] = -1e30f;
      }
      float m0 = -1e30f;
#pragma unroll
      for (int sub = 0; sub < 4; ++sub)
#pragma unroll
        for (int i = 0; i < 4; ++i) m0 = fmaxf(m0, st[qg][sub][i]);
      m0 = fmaxf(m0, __shfl_xor(m0, 16));
      m0 = fmaxf(m0, __shfl_xor(m0, 32));
      tm[qg] = m0;
    }

    // defer-rescale: if no row grew past m+8, keep old max (P <= 2^8).
    const bool noresc = __all((tm[0] <= mrow[0] + 8.f) && (tm[1] <= mrow[1] + 8.f));
    float fac[2];
#pragma unroll
    for (int qg = 0; qg < 2; ++qg) {
      const float mnew = noresc ? mrow[qg] : fmaxf(mrow[qg], tm[qg]);
      float ts = 0.f;
#pragma unroll
      for (int sub = 0; sub < 4; ++sub) {
        bf16x4 pk;
#pragma unroll
        for (int i = 0; i < 4; ++i) {
          const float p = exp2f(st[qg][sub][i] - mnew);
          ts += p;
          pk[i] = (__bf16)p;
        }
        const int swc = (sub * 16 + lk * 4) ^ ((lr & 7) << 3);
        *(bf16x4*)(&plds[w][qg * 16 + lr][swc]) = pk;
      }
      ts += __shfl_xor(ts, 16);
      ts += __shfl_xor(ts, 32);
      if (noresc) {
        lrow[qg] += ts;
      } else {
        fac[qg] = exp2f(mrow[qg] - mnew);
        lrow[qg] = lrow[qg] * fac[qg] + ts;
        mrow[qg] = mnew;
      }
    }
    if (!noresc) {
#pragma unroll
      for (int qg = 0; qg < 2; ++qg)
#pragma unroll
        for (int i = 0; i < 4; ++i) {
          const float fr = __shfl(fac[qg], lk * 4 + i);
#pragma unroll
          for (int dt = 0; dt < 4; ++dt) o[qg][dt][i] *= fr;
        }
    }

    // PV: A = P from LDS (A-frag layout, swizzled read), B = V^T rows
#pragma unroll
    for (int h2 = 0; h2 < 2; ++h2) {
      const int swc = (h2 * 32 + lk * 8) ^ ((lr & 7) << 3);
      bf16x8 pa0 = *(const bf16x8*)(&plds[w][lr][swc]);
      bf16x8 pa1 = *(const bf16x8*)(&plds[w][16 + lr][swc]);
#pragma unroll
      for (int dt = 0; dt < 4; ++dt) {
        bf16x8 vf = *(const bf16x8*)(V + (size_t)(dt * 16 + lr) * S_LEN + kb + h2 * 32 + lk * 8);
        o[0][dt] = MFMA16(pa0, vf, o[0][dt]);
        o[1][dt] = MFMA16(pa1, vf, o[1][dt]);
      }
    }
  }

  // ---- write partials ----
  if (lk == 0) {
    m_lds[w][lr]      = mrow[0];  l_lds[w][lr]      = lrow[0];
    m_lds[w][16 + lr] = mrow[1];  l_lds[w][16 + lr] = lrow[1];
  }
#pragma unroll
  for (int qg = 0; qg < 2; ++qg)
#pragma unroll
    for (int dt = 0; dt < 4; ++dt)
#pragma unroll
      for (int i = 0; i < 4; ++i)
        cmbO[w][qg * 16 + lk * 4 + i][dt * 16 + lr] = (__bf16)o[qg][dt][i];
  __syncthreads();

  // ---- combine: thread t handles (row = t>>3, cols g*8..g*8+7) ----
  const int row = t >> 3, g = t & 7;
  const float m0 = m_lds[0][row], m1 = m_lds[1][row], m2 = m_lds[2][row], m3 = m_lds[3][row];
  const float M = fmaxf(fmaxf(m0, m1), fmaxf(m2, m3));
  float wgt[4];
  wgt[0] = exp2f(m0 - M); wgt[1] = exp2f(m1 - M);
  wgt[2] = exp2f(m2 - M); wgt[3] = exp2f(m3 - M);
  float den = wgt[0] * l_lds[0][row] + wgt[1] * l_lds[1][row] +
              wgt[2] * l_lds[2][row] + wgt[3] * l_lds[3][row];
  const float inv = 1.0f / den;
  float vals[8];
#pragma unroll
  for (int c = 0; c < 8; ++c) vals[c] = 0.f;
#pragma unroll
  for (int w4 = 0; w4 < 4; ++w4) {
    bf16x8 v = *(const bf16x8*)(&cmbO[w4][row][g * 8]);
#pragma unroll
    for (int c = 0; c < 8; ++c) vals[c] += wgt[w4] * (float)v[c];
  }
  bf16x8 outv;
#pragma unroll
  for (int c = 0; c < 8; ++c) outv[c] = (__bf16)(vals[c] * inv);
  *(bf16x8*)(&ctx[(size_t)(qw + row) * HID + h * VD + g * 8]) = outv;
}

// ---------------- launch ----------------

extern "C" void kernel_launch(void* const* d_in, const int* in_sizes, int n_in,
                              void* d_out, int out_size, void* d_ws, size_t ws_size,
                              hipStream_t stream) {
  const float* hidden = (const float*)d_in[0];
  const int*   pos    = (const int*)d_in[1];
  const float* w_qa   = (const float*)d_in[2];
  const float* q_ln   = (const float*)d_in[3];
  const float* w_qb   = (const float*)d_in[4];
  const float* w_kva  = (const float*)d_in[5];
  const float* kv_ln  = (const float*)d_in[6];
  const float* w_kvb  = (const float*)d_in[7];
  const float* w_o    = (const float*)d_in[8];
  float* out = (float*)d_out;
  char* ws = (char*)d_ws;
  (void)in_sizes; (void)n_in; (void)out_size; (void)ws_size;

  size_t off = 0;
  auto take = [&](size_t bytes) -> char* {
    char* p = ws + off;
    off = (off + bytes + 255) & ~(size_t)255;
    return p;
  };
  bf16*  hid_bf = (bf16*)take((size_t)S_LEN * HID * 2);
  bf16*  wabT   = (bf16*)take((size_t)AB_N * HID * 2);   // [1056][2560]: wqaT | wkvaT
  bf16*  wqbT   = (bf16*)take((size_t)QB_N * QL * 2);
  bf16*  wkvbT  = (bf16*)take((size_t)KVB_N * KVL * 2);
  bf16*  woT    = (bf16*)take((size_t)HID * HID * 2);
  float* qlora  = (float*)take((size_t)S_LEN * QL * 4);
  bf16*  qa_bf  = (bf16*)take((size_t)S_LEN * QL * 2);
  bf16*  qraw   = (bf16*)take((size_t)S_LEN * QB_N * 2);
  bf16*  qfull  = (bf16*)take((size_t)NH * S_LEN * QHD * 2);
  float* ckv    = (float*)take((size_t)S_LEN * CKV_N * 4);
  bf16*  ckv_bf = (bf16*)take((size_t)S_LEN * KVL * 2);
  bf16*  kpe    = (bf16*)take((size_t)S_LEN * RD * 2);
  bf16*  kv_bf  = (bf16*)take((size_t)S_LEN * KVB_N * 2);
  bf16*  kfull  = (bf16*)take((size_t)NH * S_LEN * QHD * 2);
  bf16*  vt     = (bf16*)take((size_t)NH * VD * S_LEN * 2);
  bf16*  ctx    = (bf16*)take((size_t)S_LEN * HID * 2);

  const dim3 tb(32, 8);
  cast_f32_bf16<<<(S_LEN * HID / 4 + 255) / 256, 256, 0, stream>>>(hidden, hid_bf, S_LEN * HID / 4);
  transpose_cast<<<dim3((QL + 31) / 32, (HID + 31) / 32), tb, 0, stream>>>(w_qa, wabT, HID, QL);
  transpose_cast<<<dim3((CKV_N + 31) / 32, (HID + 31) / 32), tb, 0, stream>>>(w_kva, wabT + (size_t)QL * HID, HID, CKV_N);
  transpose_cast<<<dim3((QB_N + 31) / 32, (QL + 31) / 32), tb, 0, stream>>>(w_qb, wqbT, QL, QB_N);
  transpose_cast<<<dim3((KVB_N + 31) / 32, (KVL + 31) / 32), tb, 0, stream>>>(w_kvb, wkvbT, KVL, KVB_N);
  transpose_cast<<<dim3((HID + 31) / 32, (HID + 31) / 32), tb, 0, stream>>>(w_o, woT, HID, HID);

  // fused qa|kva GEMM (272 blocks)
  gemm_qakva<<<dim3((AB_N + 63) / 64, S_LEN / 128), 256, 0, stream>>>(hid_bf, wabT, qlora, ckv);

  // q path
  rmsnorm_rows<<<S_LEN, 256, 0, stream>>>(qlora, q_ln, qa_bf, QL);
  gemm_bt<true, false><<<dim3(QB_N / 128, S_LEN / 128), 256, 0, stream>>>(qa_bf, wqbT, qraw, S_LEN, QB_N, QL);
  rope_q<<<S_LEN, dim3(96, 4), 0, stream>>>(qraw, pos, qfull);

  // kv path
  kv_prep<<<S_LEN, 64, 0, stream>>>(ckv, kv_ln, pos, ckv_bf, kpe);
  gemm_bt<true, false><<<dim3(KVB_N / 128, S_LEN / 128), 256, 0, stream>>>(ckv_bf, wkvbT, kv_bf, S_LEN, KVB_N, KVL);
  build_kfull<<<S_LEN, dim3(96, 4), 0, stream>>>(kv_bf, kpe, kfull);
  transpose_v<<<dim3(S_LEN / 32, VD / 32, NH), tb, 0, stream>>>(kv_bf, vt);

  // attention + output proj
  attn_kernel<<<dim3(NH, S_LEN / 32), 256, 0, stream>>>(qfull, kfull, vt, ctx);
  gemm_bt<false, false><<<dim3(HID / 128, S_LEN / 128), 256, 0, stream>>>(ctx, woT, out, S_LEN, HID, HID);
}

// Round 6
// 267.272 us; speedup vs baseline: 1.2063x; 1.2063x over previous
//
#include <hip/hip_runtime.h>
#include <hip/hip_bf16.h>

typedef __hip_bfloat16 bf16;
typedef __attribute__((ext_vector_type(8))) __bf16 bf16x8;
typedef __attribute__((ext_vector_type(4))) __bf16 bf16x4;
typedef __attribute__((ext_vector_type(4))) float f32x4;

constexpr int S_LEN = 2048;
constexpr int HID   = 2560;
constexpr int NH    = 40;
constexpr int QL    = 768;
constexpr int KVL   = 256;
constexpr int RD    = 32;
constexpr int ND    = 64;
constexpr int VD    = 64;
constexpr int QHD   = 96;                 // NOPE_D + ROPE_D
constexpr int QB_N  = NH * QHD;           // 3840
constexpr int KVB_N = NH * (ND + VD);     // 5120
constexpr int CKV_N = KVL + RD;           // 288
constexpr int AB_N  = QL + CKV_N;         // 1056 (fused qa|kva output cols)

#define MFMA16(a, b, c) __builtin_amdgcn_mfma_f32_16x16x32_bf16((a), (b), (c), 0, 0, 0)

// position_ids may arrive as int32 or int64; values are 0..2047 so sniff layout.
__device__ __forceinline__ int get_pos(const int* pos, int s) {
  bool is64 = (pos[1] == 0 && pos[2] == 1);
  return is64 ? pos[2 * s] : pos[s];
}

// ---------------- prep ----------------

__global__ void cast_f32_bf16(const float* __restrict__ src, bf16* __restrict__ dst, int n4) {
  int i = blockIdx.x * blockDim.x + threadIdx.x;
  if (i >= n4) return;
  float4 v = reinterpret_cast<const float4*>(src)[i];
  struct { bf16 a, b, c, d; } pk;
  pk.a = __float2bfloat16(v.x); pk.b = __float2bfloat16(v.y);
  pk.c = __float2bfloat16(v.z); pk.d = __float2bfloat16(v.w);
  reinterpret_cast<uint2*>(dst)[i] = *reinterpret_cast<uint2*>(&pk);
}

// src [K][N] f32 -> dst [N][K] bf16  (B^T layout for the GEMMs)
__global__ void transpose_cast(const float* __restrict__ src, bf16* __restrict__ dst, int K, int N) {
  __shared__ float tile[32][33];
  int nb = blockIdx.x * 32, kb = blockIdx.y * 32;
  int x = threadIdx.x, y = threadIdx.y; // (32,8)
#pragma unroll
  for (int j = 0; j < 4; ++j) {
    int k = kb + y + j * 8, n = nb + x;
    tile[y + j * 8][x] = (k < K && n < N) ? src[(size_t)k * N + n] : 0.f;
  }
  __syncthreads();
#pragma unroll
  for (int j = 0; j < 4; ++j) {
    int n = nb + y + j * 8, k = kb + x;
    if (n < N && k < K) dst[(size_t)n * K + k] = __float2bfloat16(tile[x][y + j * 8]);
  }
}

// ---------------- GEMM core macro bits ----------------
// stage A,B tiles: linear LDS dest, inverse-swizzled global source (rule #21)

// Generic GEMM: C[M][N] = A[M][K] * B^T[N][K], f32 or bf16 out
template<bool OBF16, bool NEDGE>
__global__ __launch_bounds__(256) void gemm_bt(const bf16* __restrict__ A,
                                               const bf16* __restrict__ B,
                                               void* __restrict__ Cv,
                                               int M, int N, int K) {
  constexpr int BM = 128, BN = 128, BK = 64;
  __shared__ __bf16 ldsA[BM * BK];
  __shared__ __bf16 ldsB[BN * BK];
  const int t = threadIdx.x;
  const int l = t & 63, w = t >> 6;
  const int lr = l & 15, lk = l >> 4;
  const int wr = w >> 1, wc = w & 1;
  const int rowbase = blockIdx.y * BM;
  const int colbase = blockIdx.x * BN;

  f32x4 acc[4][4];
#pragma unroll
  for (int m = 0; m < 4; ++m)
#pragma unroll
    for (int n = 0; n < 4; ++n) acc[m][n] = f32x4{0.f, 0.f, 0.f, 0.f};

  const int kiters = K / BK;
  for (int kt = 0; kt < kiters; ++kt) {
    const int kb = kt * BK;
#pragma unroll
    for (int it = 0; it < 4; ++it) {
      const int r  = it * 32 + w * 8 + (l >> 3);
      const int c8 = ((l & 7) * 8) ^ ((r & 7) << 3);
      const bf16* ga = A + (size_t)(rowbase + r) * K + kb + c8;
      __builtin_amdgcn_global_load_lds((const __attribute__((address_space(1))) void*)ga,
          (__attribute__((address_space(3))) void*)(ldsA + it * 2048 + w * 512), 16, 0, 0);
      int nrow = colbase + r;
      if (NEDGE) nrow = (nrow < N) ? nrow : (N - 1);
      const bf16* gb = B + (size_t)nrow * K + kb + c8;
      __builtin_amdgcn_global_load_lds((const __attribute__((address_space(1))) void*)gb,
          (__attribute__((address_space(3))) void*)(ldsB + it * 2048 + w * 512), 16, 0, 0);
    }
    __syncthreads();
#pragma unroll
    for (int kk = 0; kk < 2; ++kk) {
      bf16x8 af[4], bfr[4];
#pragma unroll
      for (int m = 0; m < 4; ++m) {
        const int row = wr * 64 + m * 16 + lr;
        const int ce  = (kk * 32 + lk * 8) ^ ((row & 7) << 3);
        af[m] = *(const bf16x8*)(ldsA + row * BK + ce);
      }
#pragma unroll
      for (int n = 0; n < 4; ++n) {
        const int row = wc * 64 + n * 16 + lr;
        const int ce  = (kk * 32 + lk * 8) ^ ((row & 7) << 3);
        bfr[n] = *(const bf16x8*)(ldsB + row * BK + ce);
      }
#pragma unroll
      for (int m = 0; m < 4; ++m)
#pragma unroll
        for (int n = 0; n < 4; ++n)
          acc[m][n] = MFMA16(af[m], bfr[n], acc[m][n]);
    }
    __syncthreads();
  }

#pragma unroll
  for (int m = 0; m < 4; ++m)
#pragma unroll
    for (int n = 0; n < 4; ++n) {
      const int col = colbase + wc * 64 + n * 16 + lr;
      if (NEDGE && col >= N) continue;
#pragma unroll
      for (int i = 0; i < 4; ++i) {
        const int row = rowbase + wr * 64 + m * 16 + lk * 4 + i;
        if (OBF16) ((bf16*)Cv)[(size_t)row * N + col] = __float2bfloat16(acc[m][n][i]);
        else       ((float*)Cv)[(size_t)row * N + col] = acc[m][n][i];
      }
    }
}

// Fused qa|kva GEMM: C[2048][1056] = hid_bf * wabT^T, BN=64 tiles.
__global__ __launch_bounds__(256) void gemm_qakva(const bf16* __restrict__ A,
                                                  const bf16* __restrict__ B,
                                                  float* __restrict__ q_out,
                                                  float* __restrict__ ckv_out) {
  constexpr int BM = 128, BK = 64, K = HID, N = AB_N;
  __shared__ __bf16 ldsA[BM * BK];
  __shared__ __bf16 ldsB[64 * BK];
  const int t = threadIdx.x;
  const int l = t & 63, w = t >> 6;
  const int lr = l & 15, lk = l >> 4;
  const int rowbase = blockIdx.y * BM;
  const int colbase = blockIdx.x * 64;

  f32x4 acc[2][4];
#pragma unroll
  for (int m = 0; m < 2; ++m)
#pragma unroll
    for (int n = 0; n < 4; ++n) acc[m][n] = f32x4{0.f, 0.f, 0.f, 0.f};

  for (int kt = 0; kt < K / BK; ++kt) {
    const int kb = kt * BK;
#pragma unroll
    for (int it = 0; it < 4; ++it) {
      const int r  = it * 32 + w * 8 + (l >> 3);
      const int c8 = ((l & 7) * 8) ^ ((r & 7) << 3);
      const bf16* ga = A + (size_t)(rowbase + r) * K + kb + c8;
      __builtin_amdgcn_global_load_lds((const __attribute__((address_space(1))) void*)ga,
          (__attribute__((address_space(3))) void*)(ldsA + it * 2048 + w * 512), 16, 0, 0);
      if (it < 2) {
        int nrow = colbase + r;
        nrow = (nrow < N) ? nrow : (N - 1);
        const bf16* gb = B + (size_t)nrow * K + kb + c8;
        __builtin_amdgcn_global_load_lds((const __attribute__((address_space(1))) void*)gb,
            (__attribute__((address_space(3))) void*)(ldsB + it * 2048 + w * 512), 16, 0, 0);
      }
    }
    __syncthreads();
#pragma unroll
    for (int kk = 0; kk < 2; ++kk) {
      bf16x8 af[2], bfr[4];
#pragma unroll
      for (int m = 0; m < 2; ++m) {
        const int row = w * 32 + m * 16 + lr;
        const int ce  = (kk * 32 + lk * 8) ^ ((row & 7) << 3);
        af[m] = *(const bf16x8*)(ldsA + row * BK + ce);
      }
#pragma unroll
      for (int n = 0; n < 4; ++n) {
        const int row = n * 16 + lr;
        const int ce  = (kk * 32 + lk * 8) ^ ((row & 7) << 3);
        bfr[n] = *(const bf16x8*)(ldsB + row * BK + ce);
      }
#pragma unroll
      for (int m = 0; m < 2; ++m)
#pragma unroll
        for (int n = 0; n < 4; ++n)
          acc[m][n] = MFMA16(af[m], bfr[n], acc[m][n]);
    }
    __syncthreads();
  }

#pragma unroll
  for (int m = 0; m < 2; ++m)
#pragma unroll
    for (int n = 0; n < 4; ++n) {
      const int col = colbase + n * 16 + lr;
#pragma unroll
      for (int i = 0; i < 4; ++i) {
        const int row = rowbase + w * 32 + m * 16 + lk * 4 + i;
        if (col < QL)       q_out[(size_t)row * QL + col] = acc[m][n][i];
        else if (col < N)   ckv_out[(size_t)row * CKV_N + (col - QL)] = acc[m][n][i];
      }
    }
}

// qb GEMM with fused RoPE + scale, writing qfull [NH][S][96] directly.
// C[2048][3840] = qa_bf * wqbT^T. 16-wide frags never straddle a head (96=6*16)
// nor a rope subregion (boundaries at 64,80,96 are 16-multiples), so the rope
// pair (d, d+16) is acc[m][n] and acc[m][n+1] of the SAME lane.
__global__ __launch_bounds__(256) void gemm_qb_rope(const bf16* __restrict__ A,
                                                    const bf16* __restrict__ B,
                                                    const float* __restrict__ ropc,
                                                    const float* __restrict__ rops,
                                                    bf16* __restrict__ qfull) {
  constexpr int BM = 128, BN = 128, BK = 64, K = QL, N = QB_N;
  __shared__ __bf16 ldsA[BM * BK];
  __shared__ __bf16 ldsB[BN * BK];
  const int t = threadIdx.x;
  const int l = t & 63, w = t >> 6;
  const int lr = l & 15, lk = l >> 4;
  const int wr = w >> 1, wc = w & 1;
  const int rowbase = blockIdx.y * BM;
  const int colbase = blockIdx.x * BN;
  const float scale = 0.14724444f; // 96^-0.5 * log2(e)

  f32x4 acc[4][4];
#pragma unroll
  for (int m = 0; m < 4; ++m)
#pragma unroll
    for (int n = 0; n < 4; ++n) acc[m][n] = f32x4{0.f, 0.f, 0.f, 0.f};

  for (int kt = 0; kt < K / BK; ++kt) {
    const int kb = kt * BK;
#pragma unroll
    for (int it = 0; it < 4; ++it) {
      const int r  = it * 32 + w * 8 + (l >> 3);
      const int c8 = ((l & 7) * 8) ^ ((r & 7) << 3);
      const bf16* ga = A + (size_t)(rowbase + r) * K + kb + c8;
      __builtin_amdgcn_global_load_lds((const __attribute__((address_space(1))) void*)ga,
          (__attribute__((address_space(3))) void*)(ldsA + it * 2048 + w * 512), 16, 0, 0);
      const bf16* gb = B + (size_t)(colbase + r) * K + kb + c8;
      __builtin_amdgcn_global_load_lds((const __attribute__((address_space(1))) void*)gb,
          (__attribute__((address_space(3))) void*)(ldsB + it * 2048 + w * 512), 16, 0, 0);
    }
    __syncthreads();
#pragma unroll
    for (int kk = 0; kk < 2; ++kk) {
      bf16x8 af[4], bfr[4];
#pragma unroll
      for (int m = 0; m < 4; ++m) {
        const int row = wr * 64 + m * 16 + lr;
        const int ce  = (kk * 32 + lk * 8) ^ ((row & 7) << 3);
        af[m] = *(const bf16x8*)(ldsA + row * BK + ce);
      }
#pragma unroll
      for (int n = 0; n < 4; ++n) {
        const int row = wc * 64 + n * 16 + lr;
        const int ce  = (kk * 32 + lk * 8) ^ ((row & 7) << 3);
        bfr[n] = *(const bf16x8*)(ldsB + row * BK + ce);
      }
#pragma unroll
      for (int m = 0; m < 4; ++m)
#pragma unroll
        for (int n = 0; n < 4; ++n)
          acc[m][n] = MFMA16(af[m], bfr[n], acc[m][n]);
    }
    __syncthreads();
  }

  // epilogue: per n-frag, class is wave-uniform (nope / rope-lo / rope-hi)
#pragma unroll
  for (int m = 0; m < 4; ++m) {
    const int rowtop = rowbase + wr * 64 + m * 16 + lk * 4;
#pragma unroll
    for (int n = 0; n < 4; ++n) {
      const int c0 = colbase + wc * 64 + n * 16; // frag base col
      const int h  = c0 / 96;
      const int d0 = c0 - h * 96;
      const size_t qb_ = ((size_t)h * S_LEN + rowtop) * QHD + d0 + lr;
      if (d0 < ND) {
#pragma unroll
        for (int i = 0; i < 4; ++i)
          qfull[qb_ + (size_t)i * QHD] = __float2bfloat16(acc[m][n][i] * scale);
      } else if (d0 == ND) { // rope-lo: out = x0*c - x1*s, x1 = acc[m][n+1]
#pragma unroll
        for (int i = 0; i < 4; ++i) {
          const float c = ropc[(rowtop + i) * 16 + lr];
          const float s = rops[(rowtop + i) * 16 + lr];
          const float x0 = acc[m][n][i], x1 = acc[m][n + 1][i];
          qfull[qb_ + (size_t)i * QHD] = __float2bfloat16((x0 * c - x1 * s) * scale);
        }
      } else { // d0 == 80, rope-hi: out = x1*c + x0*s, x0 = acc[m][n-1]
#pragma unroll
        for (int i = 0; i < 4; ++i) {
          const float c = ropc[(rowtop + i) * 16 + lr];
          const float s = rops[(rowtop + i) * 16 + lr];
          const float x1 = acc[m][n][i], x0 = acc[m][n - 1][i];
          qfull[qb_ + (size_t)i * QHD] = __float2bfloat16((x1 * c + x0 * s) * scale);
        }
      }
    }
  }
}

// kvb GEMM writing knope [NH][S][64] and vt [NH][64][S] directly.
// C[2048][5120] = ckv_bf * wkvbT^T; col tile 128 == exactly one head.
// wc=0 waves produce k_nope, wc=1 waves produce V (stored transposed).
__global__ __launch_bounds__(256) void gemm_kvb_split(const bf16* __restrict__ A,
                                                      const bf16* __restrict__ B,
                                                      bf16* __restrict__ knope,
                                                      bf16* __restrict__ vt) {
  constexpr int BM = 128, BN = 128, BK = 64, K = KVL;
  __shared__ __bf16 ldsA[BM * BK];
  __shared__ __bf16 ldsB[BN * BK];
  const int t = threadIdx.x;
  const int l = t & 63, w = t >> 6;
  const int lr = l & 15, lk = l >> 4;
  const int wr = w >> 1, wc = w & 1;
  const int rowbase = blockIdx.y * BM;
  const int h = blockIdx.x; // head == col tile
  const int colbase = h * BN;

  f32x4 acc[4][4];
#pragma unroll
  for (int m = 0; m < 4; ++m)
#pragma unroll
    for (int n = 0; n < 4; ++n) acc[m][n] = f32x4{0.f, 0.f, 0.f, 0.f};

  for (int kt = 0; kt < K / BK; ++kt) {
    const int kb = kt * BK;
#pragma unroll
    for (int it = 0; it < 4; ++it) {
      const int r  = it * 32 + w * 8 + (l >> 3);
      const int c8 = ((l & 7) * 8) ^ ((r & 7) << 3);
      const bf16* ga = A + (size_t)(rowbase + r) * K + kb + c8;
      __builtin_amdgcn_global_load_lds((const __attribute__((address_space(1))) void*)ga,
          (__attribute__((address_space(3))) void*)(ldsA + it * 2048 + w * 512), 16, 0, 0);
      const bf16* gb = B + (size_t)(colbase + r) * K + kb + c8;
      __builtin_amdgcn_global_load_lds((const __attribute__((address_space(1))) void*)gb,
          (__attribute__((address_space(3))) void*)(ldsB + it * 2048 + w * 512), 16, 0, 0);
    }
    __syncthreads();
#pragma unroll
    for (int kk = 0; kk < 2; ++kk) {
      bf16x8 af[4], bfr[4];
#pragma unroll
      for (int m = 0; m < 4; ++m) {
        const int row = wr * 64 + m * 16 + lr;
        const int ce  = (kk * 32 + lk * 8) ^ ((row & 7) << 3);
        af[m] = *(const bf16x8*)(ldsA + row * BK + ce);
      }
#pragma unroll
      for (int n = 0; n < 4; ++n) {
        const int row = wc * 64 + n * 16 + lr;
        const int ce  = (kk * 32 + lk * 8) ^ ((row & 7) << 3);
        bfr[n] = *(const bf16x8*)(ldsB + row * BK + ce);
      }
#pragma unroll
      for (int m = 0; m < 4; ++m)
#pragma unroll
        for (int n = 0; n < 4; ++n)
          acc[m][n] = MFMA16(af[m], bfr[n], acc[m][n]);
    }
    __syncthreads();
  }

#pragma unroll
  for (int m = 0; m < 4; ++m) {
    const int rowtop = rowbase + wr * 64 + m * 16 + lk * 4;
    if (wc == 0) { // k_nope -> knope[h][s][64]
#pragma unroll
      for (int n = 0; n < 4; ++n) {
        const int d = n * 16 + lr;
#pragma unroll
        for (int i = 0; i < 4; ++i)
          knope[((size_t)h * S_LEN + rowtop + i) * ND + d] = __float2bfloat16(acc[m][n][i]);
      }
    } else {        // V -> vt[h][64][S] (8B transposed stores, L2 merges)
#pragma unroll
      for (int n = 0; n < 4; ++n) {
        const int d = n * 16 + lr;
        bf16x4 pk;
#pragma unroll
        for (int i = 0; i < 4; ++i) pk[i] = (__bf16)acc[m][n][i];
        *(bf16x4*)(vt + ((size_t)h * VD + d) * S_LEN + rowtop) = pk;
      }
    }
  }
}

// ---------------- norms / prep ----------------

__global__ void rmsnorm_rows(const float* __restrict__ in, const float* __restrict__ w,
                             bf16* __restrict__ out, int C) {
  const int r = blockIdx.x;
  const float* row = in + (size_t)r * C;
  float ss = 0.f;
  for (int c = threadIdx.x; c < C; c += 256) { float v = row[c]; ss += v * v; }
#pragma unroll
  for (int d = 32; d > 0; d >>= 1) ss += __shfl_xor(ss, d);
  __shared__ float red[4];
  if ((threadIdx.x & 63) == 0) red[threadIdx.x >> 6] = ss;
  __syncthreads();
  const float tot = red[0] + red[1] + red[2] + red[3];
  const float rs = rsqrtf(tot / (float)C + 1e-6f);
  for (int c = threadIdx.x; c < C; c += 256)
    out[(size_t)r * C + c] = __float2bfloat16(row[c] * rs * w[c]);
}

// per row: rmsnorm(ckv[0:256]) -> bf16 ; rope(k_pe) -> bf16 ; rope tables
__global__ void kv_prep(const float* __restrict__ ckv, const float* __restrict__ w,
                        const int* __restrict__ pos, bf16* __restrict__ ckv_bf,
                        bf16* __restrict__ kpe, float* __restrict__ ropc,
                        float* __restrict__ rops) {
  const int s = blockIdx.x, t = threadIdx.x; // 64 threads
  const float* row = ckv + (size_t)s * CKV_N;
  float v[4]; float ss = 0.f;
#pragma unroll
  for (int j = 0; j < 4; ++j) { v[j] = row[t + 64 * j]; ss += v[j] * v[j]; }
#pragma unroll
  for (int d = 32; d > 0; d >>= 1) ss += __shfl_xor(ss, d);
  const float rs = rsqrtf(ss / (float)KVL + 1e-6f);
#pragma unroll
  for (int j = 0; j < 4; ++j)
    ckv_bf[(size_t)s * KVL + t + 64 * j] = __float2bfloat16(v[j] * rs * w[t + 64 * j]);
  if (t < 16) {
    const float x0 = row[KVL + t], x1 = row[KVL + 16 + t];
    const float p = (float)get_pos(pos, s);
    const float invf = exp2f(-(float)t * (13.2877124f / 16.f)); // 10000^(-t/16)
    const float ang = p * invf, c = cosf(ang), sn = sinf(ang);
    ropc[s * 16 + t] = c;
    rops[s * 16 + t] = sn;
    kpe[(size_t)s * RD + t]      = __float2bfloat16(x0 * c - x1 * sn);
    kpe[(size_t)s * RD + 16 + t] = __float2bfloat16(x1 * c + x0 * sn);
  }
}

// ---------------- causal flash attention ----------------
// One wave per block, 32 q rows, KVBLK=64, K prefetch, SWAPPED QK^T
// (st = mfma(K,Q) -> S^T: lane-local row reduce + 2 shfl), log2-domain
// softmax, defer-rescale, XOR-swizzled P tile. K is split: nope from
// knope[h][s][64], pe from head-shared kpe[s][32] (L1-hot).
// Grid (NH, S/32), q-tiles REVERSED (heavy first -> LPT).
__global__ __launch_bounds__(64) void attn_kernel(const bf16* __restrict__ qfull,
                                                  const bf16* __restrict__ knope,
                                                  const bf16* __restrict__ kpe,
                                                  const bf16* __restrict__ vt,
                                                  bf16* __restrict__ ctx) {
  const int h = blockIdx.x;
  const int qw = ((int)gridDim.y - 1 - (int)blockIdx.y) * 32;
  const int l = threadIdx.x;
  const int lr = l & 15, lk = l >> 4;
  const bf16* Q  = qfull + (size_t)h * S_LEN * QHD;
  const bf16* Kn = knope + (size_t)h * S_LEN * ND;
  const bf16* V  = vt + (size_t)h * VD * S_LEN;
  __shared__ __bf16 plds[32][64]; // XOR-swizzled: col ^= (lr&7)<<3

  bf16x8 qf[2][3];
#pragma unroll
  for (int qg = 0; qg < 2; ++qg)
#pragma unroll
    for (int ks = 0; ks < 3; ++ks)
      qf[qg][ks] = *(const bf16x8*)(Q + (size_t)(qw + qg * 16 + lr) * QHD + ks * 32 + lk * 8);

  f32x4 o[2][4];
  float mrow[2], lrow[2];
#pragma unroll
  for (int qg = 0; qg < 2; ++qg) {
#pragma unroll
    for (int dt = 0; dt < 4; ++dt) o[qg][dt] = f32x4{0.f, 0.f, 0.f, 0.f};
    mrow[qg] = -1e30f; lrow[qg] = 0.f;
  }

  // preload K tile 0
  bf16x8 kf[4][3];
#pragma unroll
  for (int sub = 0; sub < 4; ++sub) {
#pragma unroll
    for (int ks = 0; ks < 2; ++ks)
      kf[sub][ks] = *(const bf16x8*)(Kn + (size_t)(sub * 16 + lr) * ND + ks * 32 + lk * 8);
    kf[sub][2] = *(const bf16x8*)(kpe + (size_t)(sub * 16 + lr) * RD + lk * 8);
  }

  for (int kb = 0;; kb += 64) {
    f32x4 st[2][4];
#pragma unroll
    for (int qg = 0; qg < 2; ++qg)
#pragma unroll
      for (int sub = 0; sub < 4; ++sub) st[qg][sub] = f32x4{0.f, 0.f, 0.f, 0.f};
#pragma unroll
    for (int qg = 0; qg < 2; ++qg)
#pragma unroll
      for (int sub = 0; sub < 4; ++sub)
#pragma unroll
        for (int ks = 0; ks < 3; ++ks)
          st[qg][sub] = MFMA16(kf[sub][ks], qf[qg][ks], st[qg][sub]);

    // prefetch next K tile (hidden under softmax+PV)
    const int nkb = kb + 64;
    if (nkb <= qw) {
#pragma unroll
      for (int sub = 0; sub < 4; ++sub) {
#pragma unroll
        for (int ks = 0; ks < 2; ++ks)
          kf[sub][ks] = *(const bf16x8*)(Kn + (size_t)(nkb + sub * 16 + lr) * ND + ks * 32 + lk * 8);
        kf[sub][2] = *(const bf16x8*)(kpe + (size_t)(nkb + sub * 16 + lr) * RD + lk * 8);
      }
    }

    const bool diag = (kb + 64 > qw);
    float tm[2];
#pragma unroll
    for (int qg = 0; qg < 2; ++qg) {
      const int q = qw + qg * 16 + lr;
      if (diag) {
#pragma unroll
        for (int sub = 0; sub < 4; ++sub)
#pragma unroll
          for (int i = 0; i < 4; ++i)
            if (kb + sub * 16 + lk * 4 + i > q) st[qg][sub][i] = -1e30f;
      }
      float m0 = -1e30f;
#pragma unroll
      for (int sub = 0; sub < 4; ++sub)
#pragma unroll
        for (int i = 0; i < 4; ++i) m0 = fmaxf(m0, st[qg][sub][i]);
      m0 = fmaxf(m0, __shfl_xor(m0, 16));
      m0 = fmaxf(m0, __shfl_xor(m0, 32));
      tm[qg] = m0;
    }

    const bool noresc = __all((tm[0] <= mrow[0] + 8.f) && (tm[1] <= mrow[1] + 8.f));
    float fac[2];
#pragma unroll
    for (int qg = 0; qg < 2; ++qg) {
      const float mnew = noresc ? mrow[qg] : fmaxf(mrow[qg], tm[qg]);
      float ts = 0.f;
#pragma unroll
      for (int sub = 0; sub < 4; ++sub) {
        bf16x4 pk;
#pragma unroll
        for (int i = 0; i < 4; ++i) {
          const float p = exp2f(st[qg][sub][i] - mnew);
          ts += p;
          pk[i] = (__bf16)p;
        }
        const int swc = (sub * 16 + lk * 4) ^ ((lr & 7) << 3);
        *(bf16x4*)(&plds[qg * 16 + lr][swc]) = pk;
      }
      ts += __shfl_xor(ts, 16);
      ts += __shfl_xor(ts, 32);
      if (noresc) {
        lrow[qg] += ts;
      } else {
        fac[qg] = exp2f(mrow[qg] - mnew);
        lrow[qg] = lrow[qg] * fac[qg] + ts;
        mrow[qg] = mnew;
      }
    }
    if (!noresc) {
#pragma unroll
      for (int qg = 0; qg < 2; ++qg)
#pragma unroll
        for (int i = 0; i < 4; ++i) {
          const float fr = __shfl(fac[qg], lk * 4 + i);
#pragma unroll
          for (int dt = 0; dt < 4; ++dt) o[qg][dt][i] *= fr;
        }
    }

    // PV: A = P from LDS (swizzled read), B = V^T rows (contiguous in s)
#pragma unroll
    for (int h2 = 0; h2 < 2; ++h2) {
      const int swc = (h2 * 32 + lk * 8) ^ ((lr & 7) << 3);
      bf16x8 pa0 = *(const bf16x8*)(&plds[lr][swc]);
      bf16x8 pa1 = *(const bf16x8*)(&plds[16 + lr][swc]);
#pragma unroll
      for (int dt = 0; dt < 4; ++dt) {
        bf16x8 vf = *(const bf16x8*)(V + (size_t)(dt * 16 + lr) * S_LEN + kb + h2 * 32 + lk * 8);
        o[0][dt] = MFMA16(pa0, vf, o[0][dt]);
        o[1][dt] = MFMA16(pa1, vf, o[1][dt]);
      }
    }
    if (nkb > qw) break;
  }

#pragma unroll
  for (int qg = 0; qg < 2; ++qg) {
    const float linv = 1.0f / lrow[qg];
#pragma unroll
    for (int i = 0; i < 4; ++i) {
      const float inv = __shfl(linv, lk * 4 + i);
#pragma unroll
      for (int dt = 0; dt < 4; ++dt) {
        const int row = qw + qg * 16 + lk * 4 + i;
        const int col = h * VD + dt * 16 + lr;
        ctx[(size_t)row * HID + col] = __float2bfloat16(o[qg][dt][i] * inv);
      }
    }
  }
}

// ---------------- launch ----------------

extern "C" void kernel_launch(void* const* d_in, const int* in_sizes, int n_in,
                              void* d_out, int out_size, void* d_ws, size_t ws_size,
                              hipStream_t stream) {
  const float* hidden = (const float*)d_in[0];
  const int*   pos    = (const int*)d_in[1];
  const float* w_qa   = (const float*)d_in[2];
  const float* q_ln   = (const float*)d_in[3];
  const float* w_qb   = (const float*)d_in[4];
  const float* w_kva  = (const float*)d_in[5];
  const float* kv_ln  = (const float*)d_in[6];
  const float* w_kvb  = (const float*)d_in[7];
  const float* w_o    = (const float*)d_in[8];
  float* out = (float*)d_out;
  char* ws = (char*)d_ws;
  (void)in_sizes; (void)n_in; (void)out_size; (void)ws_size;

  size_t off = 0;
  auto take = [&](size_t bytes) -> char* {
    char* p = ws + off;
    off = (off + bytes + 255) & ~(size_t)255;
    return p;
  };
  bf16*  hid_bf = (bf16*)take((size_t)S_LEN * HID * 2);
  bf16*  wabT   = (bf16*)take((size_t)AB_N * HID * 2);   // wqaT | wkvaT
  bf16*  wqbT   = (bf16*)take((size_t)QB_N * QL * 2);
  bf16*  wkvbT  = (bf16*)take((size_t)KVB_N * KVL * 2);
  bf16*  woT    = (bf16*)take((size_t)HID * HID * 2);
  float* qlora  = (float*)take((size_t)S_LEN * QL * 4);
  bf16*  qa_bf  = (bf16*)take((size_t)S_LEN * QL * 2);
  bf16*  qfull  = (bf16*)take((size_t)NH * S_LEN * QHD * 2);
  float* ckv    = (float*)take((size_t)S_LEN * CKV_N * 4);
  bf16*  ckv_bf = (bf16*)take((size_t)S_LEN * KVL * 2);
  bf16*  kpe    = (bf16*)take((size_t)S_LEN * RD * 2);
  float* ropc   = (float*)take((size_t)S_LEN * 16 * 4);
  float* rops   = (float*)take((size_t)S_LEN * 16 * 4);
  bf16*  knope  = (bf16*)take((size_t)NH * S_LEN * ND * 2);
  bf16*  vt     = (bf16*)take((size_t)NH * VD * S_LEN * 2);
  bf16*  ctx    = (bf16*)take((size_t)S_LEN * HID * 2);

  const dim3 tb(32, 8);
  cast_f32_bf16<<<(S_LEN * HID / 4 + 255) / 256, 256, 0, stream>>>(hidden, hid_bf, S_LEN * HID / 4);
  transpose_cast<<<dim3((QL + 31) / 32, (HID + 31) / 32), tb, 0, stream>>>(w_qa, wabT, HID, QL);
  transpose_cast<<<dim3((CKV_N + 31) / 32, (HID + 31) / 32), tb, 0, stream>>>(w_kva, wabT + (size_t)QL * HID, HID, CKV_N);
  transpose_cast<<<dim3((QB_N + 31) / 32, (QL + 31) / 32), tb, 0, stream>>>(w_qb, wqbT, QL, QB_N);
  transpose_cast<<<dim3((KVB_N + 31) / 32, (KVL + 31) / 32), tb, 0, stream>>>(w_kvb, wkvbT, KVL, KVB_N);
  transpose_cast<<<dim3((HID + 31) / 32, (HID + 31) / 32), tb, 0, stream>>>(w_o, woT, HID, HID);

  // fused qa|kva GEMM
  gemm_qakva<<<dim3((AB_N + 63) / 64, S_LEN / 128), 256, 0, stream>>>(hid_bf, wabT, qlora, ckv);

  // kv prep (also builds rope tables for q path)
  kv_prep<<<S_LEN, 64, 0, stream>>>(ckv, kv_ln, pos, ckv_bf, kpe, ropc, rops);

  // q path: rmsnorm -> qb GEMM with fused rope -> qfull
  rmsnorm_rows<<<S_LEN, 256, 0, stream>>>(qlora, q_ln, qa_bf, QL);
  gemm_qb_rope<<<dim3(QB_N / 128, S_LEN / 128), 256, 0, stream>>>(qa_bf, wqbT, ropc, rops, qfull);

  // kv path: kvb GEMM with fused split/transpose -> knope, vt
  gemm_kvb_split<<<dim3(KVB_N / 128, S_LEN / 128), 256, 0, stream>>>(ckv_bf, wkvbT, knope, vt);

  // attention + output proj
  attn_kernel<<<dim3(NH, S_LEN / 32), 64, 0, stream>>>(qfull, knope, kpe, vt, ctx);
  gemm_bt<false, false><<<dim3(HID / 128, S_LEN / 128), 256, 0, stream>>>(ctx, woT, out, S_LEN, HID, HID);
}